// Round 2
// baseline (249.334 us; speedup 1.0000x reference)
//
#include <hip/hip_runtime.h>
#include <hip/hip_bf16.h>

// Problem constants (from reference):
//   V_ORIG=32000, V_NEW=8000, D=1024, R=16, N=16384
// indices: int32 [N] (harness converts int64 -> int32)
// index_map: int32 [V_NEW]
// emb_weight: f32 [V_ORIG, D]
// down: f32 [V_NEW, D, R]
// up:   f32 [V_NEW, R, D]
// out:  f32 [N, 1, D]

#define DDIM 1024
#define RDIM 16

// One block (256 threads) computes one output row for "vocab entry" v.
// If vidx == nullptr, v = blockIdx.x (dedup path: compute per-vocab row).
// Else v = vidx[blockIdx.x] (direct path: compute per-lookup row).
__global__ __launch_bounds__(256) void reparam_rows_kernel(
    const int* __restrict__ vidx,
    const int* __restrict__ index_map,
    const float* __restrict__ emb,
    const float* __restrict__ down,
    const float* __restrict__ up,
    float* __restrict__ out)
{
    const int n    = blockIdx.x;
    const int v    = vidx ? vidx[n] : n;
    const int tid  = threadIdx.x;
    const int lane = tid & 63;
    const int wid  = tid >> 6;

    const float* __restrict__ e  = emb  + (size_t)index_map[v] * DDIM;
    const float* __restrict__ dn = down + (size_t)v * (DDIM * RDIM);
    const float* __restrict__ u  = up   + (size_t)v * (RDIM * DDIM);

    // ---- Phase 1: h[r] = sum_d e[d] * down[d][r] ----
    float h[RDIM];
    #pragma unroll
    for (int r = 0; r < RDIM; ++r) h[r] = 0.0f;

    #pragma unroll
    for (int k = 0; k < 4; ++k) {
        const int d = tid + k * 256;            // 256 threads x 4 = 1024 = D
        const float ed = e[d];
        const float4* dr = (const float4*)(dn + (size_t)d * RDIM);
        #pragma unroll
        for (int j = 0; j < 4; ++j) {
            float4 q = dr[j];
            h[j*4+0] += ed * q.x;
            h[j*4+1] += ed * q.y;
            h[j*4+2] += ed * q.z;
            h[j*4+3] += ed * q.w;
        }
    }

    // Wave-level reduce (64 lanes) of the 16 partials.
    #pragma unroll
    for (int r = 0; r < RDIM; ++r) {
        float x = h[r];
        #pragma unroll
        for (int m = 1; m < 64; m <<= 1) x += __shfl_xor(x, m, 64);
        h[r] = x;
    }

    // Cross-wave reduce via LDS (4 waves).
    __shared__ float hs[4][RDIM];
    if (lane == 0) {
        #pragma unroll
        for (int r = 0; r < RDIM; ++r) hs[wid][r] = h[r];
    }
    __syncthreads();

    float hf[RDIM];
    #pragma unroll
    for (int r = 0; r < RDIM; ++r)
        hf[r] = hs[0][r] + hs[1][r] + hs[2][r] + hs[3][r];  // broadcast reads, no conflict

    // ---- Phase 2: out[d] = sum_r hf[r] * up[r][d] ----
    // Each thread owns float4 at d = tid*4; up row loads fully coalesced.
    float4 acc = make_float4(0.f, 0.f, 0.f, 0.f);
    #pragma unroll
    for (int r = 0; r < RDIM; ++r) {
        float4 uv = *(const float4*)(u + (size_t)r * DDIM + tid * 4);
        acc.x += hf[r] * uv.x;
        acc.y += hf[r] * uv.y;
        acc.z += hf[r] * uv.z;
        acc.w += hf[r] * uv.w;
    }
    *(float4*)(out + (size_t)n * DDIM + tid * 4) = acc;
}

// out[n] = rows[indices[n]]  -- one block per n, 256 threads x float4 = 4KB row
__global__ __launch_bounds__(256) void reparam_gather_kernel(
    const int* __restrict__ indices,
    const float* __restrict__ rows,
    float* __restrict__ out)
{
    const int n = blockIdx.x;
    const int v = indices[n];
    const float4* __restrict__ src = (const float4*)(rows + (size_t)v * DDIM);
    float4* __restrict__ dst = (float4*)(out + (size_t)n * DDIM);
    dst[threadIdx.x] = src[threadIdx.x];
}

extern "C" void kernel_launch(void* const* d_in, const int* in_sizes, int n_in,
                              void* d_out, int out_size, void* d_ws, size_t ws_size,
                              hipStream_t stream)
{
    const int*   indices   = (const int*)d_in[0];
    const int*   index_map = (const int*)d_in[1];
    const float* emb       = (const float*)d_in[2];
    const float* down      = (const float*)d_in[3];
    const float* up        = (const float*)d_in[4];
    float*       out       = (float*)d_out;

    const int N = in_sizes[0];     // 16384 lookups
    const int V = in_sizes[1];     // 8000 vocab entries

    const size_t rows_bytes = (size_t)V * DDIM * sizeof(float);

    if (ws_size >= rows_bytes) {
        // Dedup path: compute each vocab row once, then gather.
        float* rows = (float*)d_ws;
        reparam_rows_kernel<<<V, 256, 0, stream>>>(nullptr, index_map, emb, down, up, rows);
        reparam_gather_kernel<<<N, 256, 0, stream>>>(indices, rows, out);
    } else {
        // Fallback: compute every lookup directly (2x the factor traffic).
        reparam_rows_kernel<<<N, 256, 0, stream>>>(indices, index_map, emb, down, up, out);
    }
}

// Round 3
// 224.868 us; speedup vs baseline: 1.1088x; 1.1088x over previous
//
#include <hip/hip_runtime.h>
#include <hip/hip_bf16.h>

// ReparamEmbeddings: V_ORIG=32000, V_NEW=8000, D=1024, R=16, N=16384
// indices: int32 [N], index_map: int32 [V_NEW]
// emb_weight: f32 [V_ORIG, D], down: f32 [V_NEW, D, R], up: f32 [V_NEW, R, D]
// out: f32 [N, 1, D]
//
// Strategy: dedup via CSR. Duplicate indices (~2x) produce identical rows, so
// compute one row per TOUCHED vocab entry and write it directly to every
// output slot that references it. Avoids the 32MB intermediate write + 32MB
// gather read, and skips the ~13% of vocab entries never referenced.

#define DDIM 1024
#define RDIM 16

// ---- CSR build ----------------------------------------------------------

__global__ __launch_bounds__(256) void zero_kernel(int* p, int n) {
    int i = blockIdx.x * 256 + threadIdx.x;
    if (i < n) p[i] = 0;
}

__global__ __launch_bounds__(256) void hist_kernel(const int* __restrict__ idx,
                                                   int* __restrict__ counts, int n) {
    int i = blockIdx.x * 256 + threadIdx.x;
    if (i < n) atomicAdd(&counts[idx[i]], 1);
}

// Single-block scan over V counts -> exclusive offsets[V+1].
__global__ __launch_bounds__(1024) void scan_kernel(const int* __restrict__ counts,
                                                    int* __restrict__ offsets, int V) {
    __shared__ int part[1024];
    const int t = threadIdx.x;
    const int per = (V + 1023) / 1024;
    const int lo = t * per;
    const int hi = min(lo + per, V);
    int s = 0;
    for (int i = lo; i < hi; ++i) s += counts[i];
    part[t] = s;
    __syncthreads();
    // Hillis-Steele inclusive scan of the 1024 partials.
    for (int d = 1; d < 1024; d <<= 1) {
        int val = (t >= d) ? part[t - d] : 0;
        __syncthreads();
        part[t] += val;
        __syncthreads();
    }
    int run = (t == 0) ? 0 : part[t - 1];
    for (int i = lo; i < hi; ++i) {
        run += counts[i];
        offsets[i + 1] = run;
    }
    if (t == 0) offsets[0] = 0;
}

__global__ __launch_bounds__(256) void scatter_kernel(const int* __restrict__ idx,
                                                      const int* __restrict__ offsets,
                                                      int* __restrict__ cursor,
                                                      int* __restrict__ lists, int n) {
    int i = blockIdx.x * 256 + threadIdx.x;
    if (i < n) {
        int v = idx[i];
        int p = offsets[v] + atomicAdd(&cursor[v], 1);
        lists[p] = i;
    }
}

// ---- main compute -------------------------------------------------------
// One block per vocab entry v. Early-exits if v is never referenced.
// Phase 1: h[16] = e^T . down[v]   (thread owns r-quad, 64 d-groups)
// Phase 2: row[d] = h . up[v]      (thread owns float4 of d)
// Then writes the row to out[n] for every n in v's CSR list.
__global__ __launch_bounds__(256) void rows_csr_kernel(
    const int* __restrict__ index_map,
    const float* __restrict__ emb,
    const float* __restrict__ down,
    const float* __restrict__ up,
    const int* __restrict__ offsets,
    const int* __restrict__ lists,
    float* __restrict__ out)
{
    const int v   = blockIdx.x;
    const int off = offsets[v];
    const int cnt = offsets[v + 1] - off;
    if (cnt == 0) return;

    const int tid = threadIdx.x;
    const float* __restrict__ e  = emb  + (size_t)index_map[v] * DDIM;
    const float* __restrict__ dn = down + (size_t)v * (DDIM * RDIM);
    const float* __restrict__ u  = up   + (size_t)v * (RDIM * DDIM);

    // ---- Phase 1 ----
    // Thread handles r in [rq, rq+4) for d = dgrp + 64k, k=0..15.
    // Byte addr of down load = tid*16 + k*4096 -> fully coalesced 16B/lane.
    const int rq   = (tid & 3) * 4;
    const int dgrp = tid >> 2;          // 0..63
    float4 hp = make_float4(0.f, 0.f, 0.f, 0.f);
    #pragma unroll
    for (int k = 0; k < 16; ++k) {
        const int d = dgrp + (k << 6);
        const float ed = e[d];          // 4-way broadcast across tid&3
        float4 q = *(const float4*)(dn + (size_t)d * RDIM + rq);
        hp.x += ed * q.x;
        hp.y += ed * q.y;
        hp.z += ed * q.z;
        hp.w += ed * q.w;
    }
    // Reduce across the 16 lanes sharing (tid&3): butterfly masks 4,8,16,32.
    #pragma unroll
    for (int m = 4; m < 64; m <<= 1) {
        hp.x += __shfl_xor(hp.x, m, 64);
        hp.y += __shfl_xor(hp.y, m, 64);
        hp.z += __shfl_xor(hp.z, m, 64);
        hp.w += __shfl_xor(hp.w, m, 64);
    }
    __shared__ float hs[4][RDIM];
    const int lane = tid & 63, wid = tid >> 6;
    if (lane < 4) {
        hs[wid][rq + 0] = hp.x;
        hs[wid][rq + 1] = hp.y;
        hs[wid][rq + 2] = hp.z;
        hs[wid][rq + 3] = hp.w;
    }
    __syncthreads();
    float hf[RDIM];
    #pragma unroll
    for (int r = 0; r < RDIM; ++r)
        hf[r] = hs[0][r] + hs[1][r] + hs[2][r] + hs[3][r];   // broadcast reads

    // ---- Phase 2 ----
    float4 acc = make_float4(0.f, 0.f, 0.f, 0.f);
    #pragma unroll
    for (int r = 0; r < RDIM; ++r) {
        float4 uv = *(const float4*)(u + (size_t)r * DDIM + tid * 4);
        acc.x += hf[r] * uv.x;
        acc.y += hf[r] * uv.y;
        acc.z += hf[r] * uv.z;
        acc.w += hf[r] * uv.w;
    }

    // ---- Direct scatter-write to every referencing output slot ----
    for (int j = 0; j < cnt; ++j) {
        const int n = lists[off + j];   // broadcast scalar load
        *(float4*)(out + (size_t)n * DDIM + tid * 4) = acc;
    }
}

// Fallback (tiny ws): compute each lookup independently.
__global__ __launch_bounds__(256) void rows_direct_kernel(
    const int* __restrict__ indices,
    const int* __restrict__ index_map,
    const float* __restrict__ emb,
    const float* __restrict__ down,
    const float* __restrict__ up,
    float* __restrict__ out)
{
    const int n   = blockIdx.x;
    const int v   = indices[n];
    const int tid = threadIdx.x;
    const float* __restrict__ e  = emb  + (size_t)index_map[v] * DDIM;
    const float* __restrict__ dn = down + (size_t)v * (DDIM * RDIM);
    const float* __restrict__ u  = up   + (size_t)v * (RDIM * DDIM);

    const int rq   = (tid & 3) * 4;
    const int dgrp = tid >> 2;
    float4 hp = make_float4(0.f, 0.f, 0.f, 0.f);
    #pragma unroll
    for (int k = 0; k < 16; ++k) {
        const int d = dgrp + (k << 6);
        const float ed = e[d];
        float4 q = *(const float4*)(dn + (size_t)d * RDIM + rq);
        hp.x += ed * q.x; hp.y += ed * q.y; hp.z += ed * q.z; hp.w += ed * q.w;
    }
    #pragma unroll
    for (int m = 4; m < 64; m <<= 1) {
        hp.x += __shfl_xor(hp.x, m, 64);
        hp.y += __shfl_xor(hp.y, m, 64);
        hp.z += __shfl_xor(hp.z, m, 64);
        hp.w += __shfl_xor(hp.w, m, 64);
    }
    __shared__ float hs[4][RDIM];
    const int lane = tid & 63, wid = tid >> 6;
    if (lane < 4) {
        hs[wid][rq + 0] = hp.x; hs[wid][rq + 1] = hp.y;
        hs[wid][rq + 2] = hp.z; hs[wid][rq + 3] = hp.w;
    }
    __syncthreads();
    float hf[RDIM];
    #pragma unroll
    for (int r = 0; r < RDIM; ++r)
        hf[r] = hs[0][r] + hs[1][r] + hs[2][r] + hs[3][r];

    float4 acc = make_float4(0.f, 0.f, 0.f, 0.f);
    #pragma unroll
    for (int r = 0; r < RDIM; ++r) {
        float4 uv = *(const float4*)(u + (size_t)r * DDIM + tid * 4);
        acc.x += hf[r] * uv.x; acc.y += hf[r] * uv.y;
        acc.z += hf[r] * uv.z; acc.w += hf[r] * uv.w;
    }
    *(float4*)(out + (size_t)n * DDIM + tid * 4) = acc;
}

extern "C" void kernel_launch(void* const* d_in, const int* in_sizes, int n_in,
                              void* d_out, int out_size, void* d_ws, size_t ws_size,
                              hipStream_t stream)
{
    const int*   indices   = (const int*)d_in[0];
    const int*   index_map = (const int*)d_in[1];
    const float* emb       = (const float*)d_in[2];
    const float* down      = (const float*)d_in[3];
    const float* up        = (const float*)d_in[4];
    float*       out       = (float*)d_out;

    const int N = in_sizes[0];
    const int V = in_sizes[1];

    // ws layout: counts[V] | cursor[V] | offsets[V+1] | lists[N]
    const size_t ws_need = (size_t)(2 * V + (V + 1) + N) * sizeof(int);

    if (ws_size >= ws_need) {
        int* counts  = (int*)d_ws;
        int* cursor  = counts + V;
        int* offsets = cursor + V;
        int* lists   = offsets + (V + 1);

        zero_kernel<<<(2 * V + 255) / 256, 256, 0, stream>>>(counts, 2 * V);
        hist_kernel<<<(N + 255) / 256, 256, 0, stream>>>(indices, counts, N);
        scan_kernel<<<1, 1024, 0, stream>>>(counts, offsets, V);
        scatter_kernel<<<(N + 255) / 256, 256, 0, stream>>>(indices, offsets, cursor, lists, N);
        rows_csr_kernel<<<V, 256, 0, stream>>>(index_map, emb, down, up, offsets, lists, out);
    } else {
        rows_direct_kernel<<<N, 256, 0, stream>>>(indices, index_map, emb, down, up, out);
    }
}

// Round 4
// 223.747 us; speedup vs baseline: 1.1144x; 1.0050x over previous
//
#include <hip/hip_runtime.h>
#include <hip/hip_bf16.h>

// ReparamEmbeddings: V_ORIG=32000, V_NEW=8000, D=1024, R=16, N=16384
// indices: int32 [N], index_map: int32 [V_NEW]
// emb_weight: f32 [V_ORIG, D], down: f32 [V_NEW, D, R], up: f32 [V_NEW, R, D]
// out: f32 [N, 1, D]
//
// Strategy: dedup via CSR. Duplicate indices (~2x) produce identical rows, so
// compute one row per TOUCHED vocab entry and write it directly to every
// output slot that references it. Avoids the 32MB intermediate write + 32MB
// gather read, and skips the ~13% of vocab entries never referenced.

#define DDIM 1024
#define RDIM 16

// ---- CSR build ----------------------------------------------------------

__global__ __launch_bounds__(256) void zero_kernel(int* p, int n) {
    int i = blockIdx.x * 256 + threadIdx.x;
    if (i < n) p[i] = 0;
}

__global__ __launch_bounds__(256) void hist_kernel(const int* __restrict__ idx,
                                                   int* __restrict__ counts, int n) {
    int i = blockIdx.x * 256 + threadIdx.x;
    if (i < n) atomicAdd(&counts[idx[i]], 1);
}

// Single-block scan over V counts -> exclusive offsets[V+1].
__global__ __launch_bounds__(1024) void scan_kernel(const int* __restrict__ counts,
                                                    int* __restrict__ offsets, int V) {
    __shared__ int part[1024];
    const int t = threadIdx.x;
    const int per = (V + 1023) / 1024;
    const int lo = t * per;
    const int hi = min(lo + per, V);
    int s = 0;
    for (int i = lo; i < hi; ++i) s += counts[i];
    part[t] = s;
    __syncthreads();
    // Hillis-Steele inclusive scan of the 1024 partials.
    for (int d = 1; d < 1024; d <<= 1) {
        int val = (t >= d) ? part[t - d] : 0;
        __syncthreads();
        part[t] += val;
        __syncthreads();
    }
    int run = (t == 0) ? 0 : part[t - 1];
    for (int i = lo; i < hi; ++i) {
        run += counts[i];
        offsets[i + 1] = run;
    }
    if (t == 0) offsets[0] = 0;
}

__global__ __launch_bounds__(256) void scatter_kernel(const int* __restrict__ idx,
                                                      const int* __restrict__ offsets,
                                                      int* __restrict__ cursor,
                                                      int* __restrict__ lists, int n) {
    int i = blockIdx.x * 256 + threadIdx.x;
    if (i < n) {
        int v = idx[i];
        int p = offsets[v] + atomicAdd(&cursor[v], 1);
        lists[p] = i;
    }
}

// ---- main compute -------------------------------------------------------
// One block per vocab entry v. Early-exits if v is never referenced.
// Phase 1: h[16] = e^T . down[v]   (thread owns r-quad, 64 d-groups)
// Phase 2: row[d] = h . up[v]      (thread owns float4 of d)
// Then writes the row to out[n] for every n in v's CSR list.
__global__ __launch_bounds__(256) void rows_csr_kernel(
    const int* __restrict__ index_map,
    const float* __restrict__ emb,
    const float* __restrict__ down,
    const float* __restrict__ up,
    const int* __restrict__ offsets,
    const int* __restrict__ lists,
    float* __restrict__ out)
{
    const int v   = blockIdx.x;
    const int off = offsets[v];
    const int cnt = offsets[v + 1] - off;
    if (cnt == 0) return;

    const int tid = threadIdx.x;
    const float* __restrict__ e  = emb  + (size_t)index_map[v] * DDIM;
    const float* __restrict__ dn = down + (size_t)v * (DDIM * RDIM);
    const float* __restrict__ u  = up   + (size_t)v * (RDIM * DDIM);

    // ---- Phase 1 ----
    // Thread handles r in [rq, rq+4) for d = dgrp + 64k, k=0..15.
    // Byte addr of down load = tid*16 + k*4096 -> fully coalesced 16B/lane.
    const int rq   = (tid & 3) * 4;
    const int dgrp = tid >> 2;          // 0..63
    float4 hp = make_float4(0.f, 0.f, 0.f, 0.f);
    #pragma unroll
    for (int k = 0; k < 16; ++k) {
        const int d = dgrp + (k << 6);
        const float ed = e[d];          // 4-way broadcast across tid&3
        float4 q = *(const float4*)(dn + (size_t)d * RDIM + rq);
        hp.x += ed * q.x;
        hp.y += ed * q.y;
        hp.z += ed * q.z;
        hp.w += ed * q.w;
    }
    // Reduce across the 16 lanes sharing (tid&3): butterfly masks 4,8,16,32.
    #pragma unroll
    for (int m = 4; m < 64; m <<= 1) {
        hp.x += __shfl_xor(hp.x, m, 64);
        hp.y += __shfl_xor(hp.y, m, 64);
        hp.z += __shfl_xor(hp.z, m, 64);
        hp.w += __shfl_xor(hp.w, m, 64);
    }
    __shared__ float hs[4][RDIM];
    const int lane = tid & 63, wid = tid >> 6;
    if (lane < 4) {
        hs[wid][rq + 0] = hp.x;
        hs[wid][rq + 1] = hp.y;
        hs[wid][rq + 2] = hp.z;
        hs[wid][rq + 3] = hp.w;
    }
    __syncthreads();
    float hf[RDIM];
    #pragma unroll
    for (int r = 0; r < RDIM; ++r)
        hf[r] = hs[0][r] + hs[1][r] + hs[2][r] + hs[3][r];   // broadcast reads

    // ---- Phase 2 ----
    float4 acc = make_float4(0.f, 0.f, 0.f, 0.f);
    #pragma unroll
    for (int r = 0; r < RDIM; ++r) {
        float4 uv = *(const float4*)(u + (size_t)r * DDIM + tid * 4);
        acc.x += hf[r] * uv.x;
        acc.y += hf[r] * uv.y;
        acc.z += hf[r] * uv.z;
        acc.w += hf[r] * uv.w;
    }

    // ---- Direct scatter-write to every referencing output slot ----
    for (int j = 0; j < cnt; ++j) {
        const int n = lists[off + j];   // broadcast scalar load
        *(float4*)(out + (size_t)n * DDIM + tid * 4) = acc;
    }
}

// Fallback (tiny ws): compute each lookup independently.
__global__ __launch_bounds__(256) void rows_direct_kernel(
    const int* __restrict__ indices,
    const int* __restrict__ index_map,
    const float* __restrict__ emb,
    const float* __restrict__ down,
    const float* __restrict__ up,
    float* __restrict__ out)
{
    const int n   = blockIdx.x;
    const int v   = indices[n];
    const int tid = threadIdx.x;
    const float* __restrict__ e  = emb  + (size_t)index_map[v] * DDIM;
    const float* __restrict__ dn = down + (size_t)v * (DDIM * RDIM);
    const float* __restrict__ u  = up   + (size_t)v * (RDIM * DDIM);

    const int rq   = (tid & 3) * 4;
    const int dgrp = tid >> 2;
    float4 hp = make_float4(0.f, 0.f, 0.f, 0.f);
    #pragma unroll
    for (int k = 0; k < 16; ++k) {
        const int d = dgrp + (k << 6);
        const float ed = e[d];
        float4 q = *(const float4*)(dn + (size_t)d * RDIM + rq);
        hp.x += ed * q.x; hp.y += ed * q.y; hp.z += ed * q.z; hp.w += ed * q.w;
    }
    #pragma unroll
    for (int m = 4; m < 64; m <<= 1) {
        hp.x += __shfl_xor(hp.x, m, 64);
        hp.y += __shfl_xor(hp.y, m, 64);
        hp.z += __shfl_xor(hp.z, m, 64);
        hp.w += __shfl_xor(hp.w, m, 64);
    }
    __shared__ float hs[4][RDIM];
    const int lane = tid & 63, wid = tid >> 6;
    if (lane < 4) {
        hs[wid][rq + 0] = hp.x; hs[wid][rq + 1] = hp.y;
        hs[wid][rq + 2] = hp.z; hs[wid][rq + 3] = hp.w;
    }
    __syncthreads();
    float hf[RDIM];
    #pragma unroll
    for (int r = 0; r < RDIM; ++r)
        hf[r] = hs[0][r] + hs[1][r] + hs[2][r] + hs[3][r];

    float4 acc = make_float4(0.f, 0.f, 0.f, 0.f);
    #pragma unroll
    for (int r = 0; r < RDIM; ++r) {
        float4 uv = *(const float4*)(u + (size_t)r * DDIM + tid * 4);
        acc.x += hf[r] * uv.x; acc.y += hf[r] * uv.y;
        acc.z += hf[r] * uv.z; acc.w += hf[r] * uv.w;
    }
    *(float4*)(out + (size_t)n * DDIM + tid * 4) = acc;
}

extern "C" void kernel_launch(void* const* d_in, const int* in_sizes, int n_in,
                              void* d_out, int out_size, void* d_ws, size_t ws_size,
                              hipStream_t stream)
{
    const int*   indices   = (const int*)d_in[0];
    const int*   index_map = (const int*)d_in[1];
    const float* emb       = (const float*)d_in[2];
    const float* down      = (const float*)d_in[3];
    const float* up        = (const float*)d_in[4];
    float*       out       = (float*)d_out;

    const int N = in_sizes[0];
    const int V = in_sizes[1];

    // ws layout: counts[V] | cursor[V] | offsets[V+1] | lists[N]
    const size_t ws_need = (size_t)(2 * V + (V + 1) + N) * sizeof(int);

    if (ws_size >= ws_need) {
        int* counts  = (int*)d_ws;
        int* cursor  = counts + V;
        int* offsets = cursor + V;
        int* lists   = offsets + (V + 1);

        zero_kernel<<<(2 * V + 255) / 256, 256, 0, stream>>>(counts, 2 * V);
        hist_kernel<<<(N + 255) / 256, 256, 0, stream>>>(indices, counts, N);
        scan_kernel<<<1, 1024, 0, stream>>>(counts, offsets, V);
        scatter_kernel<<<(N + 255) / 256, 256, 0, stream>>>(indices, offsets, cursor, lists, N);
        rows_csr_kernel<<<V, 256, 0, stream>>>(index_map, emb, down, up, offsets, lists, out);
    } else {
        rows_direct_kernel<<<N, 256, 0, stream>>>(indices, index_map, emb, down, up, out);
    }
}

// Round 5
// 214.559 us; speedup vs baseline: 1.1621x; 1.0428x over previous
//
#include <hip/hip_runtime.h>
#include <hip/hip_bf16.h>

// ReparamEmbeddings: V_ORIG=32000, V_NEW=8000, D=1024, R=16, N=16384
// indices: int32 [N], index_map: int32 [V_NEW]
// emb_weight: f32 [V_ORIG, D], down: f32 [V_NEW, D, R], up: f32 [V_NEW, R, D]
// out: f32 [N, 1, D]
//
// Dedup strategy: duplicate indices produce identical rows. Group output
// slots per vocab entry with a linked list (head[v] / next[n]) built by
// atomicExch -- no scan, no cursor, 2 tiny kernels. Main kernel computes
// one row per touched v and writes it to every slot in the chain. Chain
// order is nondeterministic but the written VALUES are identical per v,
// so d_out is deterministic.

#define DDIM 1024
#define RDIM 16

__global__ __launch_bounds__(256) void init_head_kernel(int* __restrict__ head, int V) {
    int v = blockIdx.x * 256 + threadIdx.x;
    if (v < V) head[v] = -1;
}

__global__ __launch_bounds__(256) void link_kernel(const int* __restrict__ idx,
                                                   int* __restrict__ head,
                                                   int* __restrict__ next, int n) {
    int i = blockIdx.x * 256 + threadIdx.x;
    if (i < n) next[i] = atomicExch(&head[idx[i]], i);
}

// One block per vocab entry v. Early-exit if untouched.
// Phase 1: h[16] = e^T . down[v]  (thread owns r-quad rq, d-slice dgrp+64k)
// Phase 2: row = h . up[v]        (thread owns float4 at d = tid*4)
// All 48 loads are staged into named register arrays BEFORE any compute so
// they are simultaneously in flight (defeats the compiler's 36-VGPR
// serialization seen in the previous round).
__global__ __launch_bounds__(256) void rows_ll_kernel(
    const int* __restrict__ index_map,
    const float* __restrict__ emb,
    const float* __restrict__ down,
    const float* __restrict__ up,
    const int* __restrict__ head,
    const int* __restrict__ next,
    float* __restrict__ out)
{
    const int v = blockIdx.x;
    int n0 = head[v];
    if (n0 < 0) return;                  // vocab entry never referenced

    const int tid  = threadIdx.x;
    const float* __restrict__ e  = emb  + (size_t)index_map[v] * DDIM;
    const float* __restrict__ dn = down + (size_t)v * (DDIM * RDIM);
    const float* __restrict__ u  = up   + (size_t)v * (RDIM * DDIM);

    const int rq   = (tid & 3) * 4;      // r-quad this thread accumulates
    const int dgrp = tid >> 2;           // 0..63

    // ---- Stage ALL loads (independent; maximize outstanding VMEM) ----
    float4 dq[16];
    float  ev[16];
    #pragma unroll
    for (int k = 0; k < 16; ++k) {
        const int d = dgrp + (k << 6);
        dq[k] = *(const float4*)(dn + (size_t)d * RDIM + rq);  // tid*16 + k*4096: coalesced
        ev[k] = e[d];
    }
    float4 uvec[RDIM];
    #pragma unroll
    for (int r = 0; r < RDIM; ++r)
        uvec[r] = *(const float4*)(u + (size_t)r * DDIM + tid * 4);  // coalesced rows

    // ---- Phase 1 FMAs ----
    float4 hp = make_float4(0.f, 0.f, 0.f, 0.f);
    #pragma unroll
    for (int k = 0; k < 16; ++k) {
        hp.x += ev[k] * dq[k].x;
        hp.y += ev[k] * dq[k].y;
        hp.z += ev[k] * dq[k].z;
        hp.w += ev[k] * dq[k].w;
    }
    // Reduce across the 16 lanes sharing rq: butterfly masks 4..32.
    #pragma unroll
    for (int m = 4; m < 64; m <<= 1) {
        hp.x += __shfl_xor(hp.x, m, 64);
        hp.y += __shfl_xor(hp.y, m, 64);
        hp.z += __shfl_xor(hp.z, m, 64);
        hp.w += __shfl_xor(hp.w, m, 64);
    }
    __shared__ float hs[4][RDIM];
    const int lane = tid & 63, wid = tid >> 6;
    if (lane < 4) {
        hs[wid][rq + 0] = hp.x;
        hs[wid][rq + 1] = hp.y;
        hs[wid][rq + 2] = hp.z;
        hs[wid][rq + 3] = hp.w;
    }
    __syncthreads();
    float hf[RDIM];
    #pragma unroll
    for (int r = 0; r < RDIM; ++r)
        hf[r] = hs[0][r] + hs[1][r] + hs[2][r] + hs[3][r];   // broadcast reads

    // ---- Phase 2 (up already in registers) ----
    float4 acc = make_float4(0.f, 0.f, 0.f, 0.f);
    #pragma unroll
    for (int r = 0; r < RDIM; ++r) {
        acc.x += hf[r] * uvec[r].x;
        acc.y += hf[r] * uvec[r].y;
        acc.z += hf[r] * uvec[r].z;
        acc.w += hf[r] * uvec[r].w;
    }

    // ---- Walk the chain, write row to every referencing slot ----
    int n = n0;
    while (n >= 0) {
        *(float4*)(out + (size_t)n * DDIM + tid * 4) = acc;
        n = next[n];                     // wave-uniform load -> broadcast
    }
}

// Fallback (no ws): compute each lookup independently.
__global__ __launch_bounds__(256) void rows_direct_kernel(
    const int* __restrict__ indices,
    const int* __restrict__ index_map,
    const float* __restrict__ emb,
    const float* __restrict__ down,
    const float* __restrict__ up,
    float* __restrict__ out)
{
    const int nn  = blockIdx.x;
    const int v   = indices[nn];
    const int tid = threadIdx.x;
    const float* __restrict__ e  = emb  + (size_t)index_map[v] * DDIM;
    const float* __restrict__ dn = down + (size_t)v * (DDIM * RDIM);
    const float* __restrict__ u  = up   + (size_t)v * (RDIM * DDIM);

    const int rq   = (tid & 3) * 4;
    const int dgrp = tid >> 2;
    float4 dq[16];
    float  ev[16];
    #pragma unroll
    for (int k = 0; k < 16; ++k) {
        const int d = dgrp + (k << 6);
        dq[k] = *(const float4*)(dn + (size_t)d * RDIM + rq);
        ev[k] = e[d];
    }
    float4 uvec[RDIM];
    #pragma unroll
    for (int r = 0; r < RDIM; ++r)
        uvec[r] = *(const float4*)(u + (size_t)r * DDIM + tid * 4);

    float4 hp = make_float4(0.f, 0.f, 0.f, 0.f);
    #pragma unroll
    for (int k = 0; k < 16; ++k) {
        hp.x += ev[k] * dq[k].x; hp.y += ev[k] * dq[k].y;
        hp.z += ev[k] * dq[k].z; hp.w += ev[k] * dq[k].w;
    }
    #pragma unroll
    for (int m = 4; m < 64; m <<= 1) {
        hp.x += __shfl_xor(hp.x, m, 64);
        hp.y += __shfl_xor(hp.y, m, 64);
        hp.z += __shfl_xor(hp.z, m, 64);
        hp.w += __shfl_xor(hp.w, m, 64);
    }
    __shared__ float hs[4][RDIM];
    const int lane = tid & 63, wid = tid >> 6;
    if (lane < 4) {
        hs[wid][rq + 0] = hp.x; hs[wid][rq + 1] = hp.y;
        hs[wid][rq + 2] = hp.z; hs[wid][rq + 3] = hp.w;
    }
    __syncthreads();
    float hf[RDIM];
    #pragma unroll
    for (int r = 0; r < RDIM; ++r)
        hf[r] = hs[0][r] + hs[1][r] + hs[2][r] + hs[3][r];

    float4 acc = make_float4(0.f, 0.f, 0.f, 0.f);
    #pragma unroll
    for (int r = 0; r < RDIM; ++r) {
        acc.x += hf[r] * uvec[r].x; acc.y += hf[r] * uvec[r].y;
        acc.z += hf[r] * uvec[r].z; acc.w += hf[r] * uvec[r].w;
    }
    *(float4*)(out + (size_t)nn * DDIM + tid * 4) = acc;
}

extern "C" void kernel_launch(void* const* d_in, const int* in_sizes, int n_in,
                              void* d_out, int out_size, void* d_ws, size_t ws_size,
                              hipStream_t stream)
{
    const int*   indices   = (const int*)d_in[0];
    const int*   index_map = (const int*)d_in[1];
    const float* emb       = (const float*)d_in[2];
    const float* down      = (const float*)d_in[3];
    const float* up        = (const float*)d_in[4];
    float*       out       = (float*)d_out;

    const int N = in_sizes[0];
    const int V = in_sizes[1];

    // ws layout: head[V] | next[N]
    const size_t ws_need = (size_t)(V + N) * sizeof(int);

    if (ws_size >= ws_need) {
        int* head = (int*)d_ws;
        int* next = head + V;
        init_head_kernel<<<(V + 255) / 256, 256, 0, stream>>>(head, V);
        link_kernel<<<(N + 255) / 256, 256, 0, stream>>>(indices, head, next, N);
        rows_ll_kernel<<<V, 256, 0, stream>>>(index_map, emb, down, up, head, next, out);
    } else {
        rows_direct_kernel<<<N, 256, 0, stream>>>(indices, index_map, emb, down, up, out);
    }
}